// Round 4
// baseline (234.523 us; speedup 1.0000x reference)
//
#include <hip/hip_runtime.h>

#define TPB 256
#define NWAVE (TPB / 64)

typedef float vf4 __attribute__((ext_vector_type(4)));
typedef int   vi2 __attribute__((ext_vector_type(2)));
typedef int   vi4 __attribute__((ext_vector_type(4)));

struct SegInfo {
    int e0, e1, e2, e3, e4;       // block-range ends: bond, angle, torsion, inversion, LJ
    int NB, NA, NT, NI, NC;
    int N;
};

// One atom's 8 batch replicas, packed: float[24] = 6 x dwordx4 (96 B).
struct Slot { vf4 t[6]; };

__device__ __forceinline__ float sc(const Slot& s, int i) { return s.t[i >> 2][i & 3]; }
__device__ __forceinline__ void  ss(Slot& s, int i, float v) { s.t[i >> 2][i & 3] = v; }

__device__ __forceinline__ float clamp1(float x) {
    return fminf(fmaxf(x, -0.999999f), 0.999999f);
}

__device__ __forceinline__ float ntf(const float* p) { return __builtin_nontemporal_load(p); }
__device__ __forceinline__ int   nti(const int* p)   { return __builtin_nontemporal_load(p); }

template <bool USE_WS>
__device__ __forceinline__ Slot loadSlot(const float* __restrict__ cw,
                                         const float* __restrict__ coords,
                                         int N, int atom) {
    Slot s;
    if (USE_WS) {
        const vf4* p = (const vf4*)(cw + (size_t)atom * 24);
#pragma unroll
        for (int j = 0; j < 6; j++) s.t[j] = p[j];
    } else {
#pragma unroll
        for (int b = 0; b < 8; b++) {
            const float* sp = coords + ((size_t)b * N + atom) * 3;
            ss(s, 3 * b, sp[0]); ss(s, 3 * b + 1, sp[1]); ss(s, 3 * b + 2, sp[2]);
        }
    }
    return s;
}

// coords (B,N,3) -> cw float[atom][24]; also zeroes d_out.
__global__ void __launch_bounds__(TPB) transpose_coords(const float* __restrict__ coords,
                                                        float* __restrict__ cw,
                                                        float* __restrict__ out, int N) {
    const int a = blockIdx.x * TPB + threadIdx.x;
    if (blockIdx.x == 0 && threadIdx.x < 8) out[threadIdx.x] = 0.f;
    if (a >= N) return;
    float c[24];
#pragma unroll
    for (int b = 0; b < 8; b++) {
        const float* sp = coords + ((size_t)b * N + a) * 3;
        c[3 * b] = ntf(sp); c[3 * b + 1] = ntf(sp + 1); c[3 * b + 2] = ntf(sp + 2);
    }
    vf4* dst = (vf4*)(cw + (size_t)a * 24);
#pragma unroll
    for (int j = 0; j < 6; j++) {
        vf4 v;
        v.x = c[4 * j]; v.y = c[4 * j + 1]; v.z = c[4 * j + 2]; v.w = c[4 * j + 3];
        dst[j] = v;
    }
}

template <bool USE_WS>
__global__ void __launch_bounds__(TPB, 3) uff_kernel(
    const float* __restrict__ coords, const float* __restrict__ cw,
    const int* __restrict__ bidx, const float* __restrict__ br0, const float* __restrict__ bk,
    const int* __restrict__ aidx, const float* __restrict__ ak,
    const float* __restrict__ ac0, const float* __restrict__ ac1, const float* __restrict__ ac2,
    const int* __restrict__ tidx, const float* __restrict__ tk,
    const int* __restrict__ tord, const float* __restrict__ tcos,
    const int* __restrict__ iidx, const float* __restrict__ ik,
    const float* __restrict__ ic0, const float* __restrict__ ic1, const float* __restrict__ ic2,
    const int* __restrict__ nidx, const float* __restrict__ vmin,
    const float* __restrict__ vdep, const float* __restrict__ vthr,
    float* __restrict__ out, SegInfo s)
{
    float acc[8];
#pragma unroll
    for (int b = 0; b < 8; b++) acc[b] = 0.f;

    const int blk = blockIdx.x;
    const int tid = threadIdx.x;
    const int N = s.N;

    if (blk < s.e0) {
        // ---------------- bond stretch ----------------
        const int t = blk * TPB + tid;
        if (t < s.NB) {
            const vi2 ij = __builtin_nontemporal_load((const vi2*)bidx + t);
            const float r0 = ntf(br0 + t), k = ntf(bk + t);
            Slot ci = loadSlot<USE_WS>(cw, coords, N, ij.x);
            Slot cj = loadSlot<USE_WS>(cw, coords, N, ij.y);
#pragma unroll
            for (int b = 0; b < 8; b++) {
                float dx = sc(ci, 3 * b) - sc(cj, 3 * b);
                float dy = sc(ci, 3 * b + 1) - sc(cj, 3 * b + 1);
                float dz = sc(ci, 3 * b + 2) - sc(cj, 3 * b + 2);
                float dd = sqrtf(dx * dx + dy * dy + dz * dz) - r0;
                acc[b] += 0.5f * k * dd * dd;
            }
        }
    } else if (blk < s.e1) {
        // ---------------- angle bend ----------------
        const int t = (blk - s.e0) * TPB + tid;
        if (t < s.NA) {
            const int i1 = nti(aidx + 3 * t), i2 = nti(aidx + 3 * t + 1), i3 = nti(aidx + 3 * t + 2);
            const float k = ntf(ak + t), c0 = ntf(ac0 + t), c1 = ntf(ac1 + t), c2 = ntf(ac2 + t);
            Slot P = loadSlot<USE_WS>(cw, coords, N, i1);
            Slot Q = loadSlot<USE_WS>(cw, coords, N, i2);
            Slot R = loadSlot<USE_WS>(cw, coords, N, i3);
#pragma unroll
            for (int b = 0; b < 8; b++) {
                float ax = sc(P, 3 * b) - sc(Q, 3 * b);
                float ay = sc(P, 3 * b + 1) - sc(Q, 3 * b + 1);
                float az = sc(P, 3 * b + 2) - sc(Q, 3 * b + 2);
                float bx = sc(R, 3 * b) - sc(Q, 3 * b);
                float by = sc(R, 3 * b + 1) - sc(Q, 3 * b + 1);
                float bz = sc(R, 3 * b + 2) - sc(Q, 3 * b + 2);
                float dot = ax * bx + ay * by + az * bz;
                float nn = (ax * ax + ay * ay + az * az) * (bx * bx + by * by + bz * bz);
                float ct = clamp1(dot * rsqrtf(fmaxf(nn, 1e-24f)));
                float cs = ct * ct;
                float sb = fmaxf(1.f - cs, 1e-12f);
                acc[b] += k * (c0 + c1 * ct + c2 * (cs - sb));
            }
        }
    } else if (blk < s.e2) {
        // ---------------- torsion ----------------
        const int t = (blk - s.e1) * TPB + tid;
        if (t < s.NT) {
            const vi4 q = __builtin_nontemporal_load((const vi4*)tidx + t);
            const float V = ntf(tk + t), ctm = ntf(tcos + t);
            const int ord = nti(tord + t);
            Slot P1 = loadSlot<USE_WS>(cw, coords, N, q.x);
            Slot P2 = loadSlot<USE_WS>(cw, coords, N, q.y);
            Slot P3 = loadSlot<USE_WS>(cw, coords, N, q.z);
            Slot P4 = loadSlot<USE_WS>(cw, coords, N, q.w);
#pragma unroll
            for (int b = 0; b < 8; b++) {
                float b1x = sc(P2, 3 * b) - sc(P1, 3 * b);
                float b1y = sc(P2, 3 * b + 1) - sc(P1, 3 * b + 1);
                float b1z = sc(P2, 3 * b + 2) - sc(P1, 3 * b + 2);
                float b2x = sc(P3, 3 * b) - sc(P2, 3 * b);
                float b2y = sc(P3, 3 * b + 1) - sc(P2, 3 * b + 1);
                float b2z = sc(P3, 3 * b + 2) - sc(P2, 3 * b + 2);
                float b3x = sc(P4, 3 * b) - sc(P3, 3 * b);
                float b3y = sc(P4, 3 * b + 1) - sc(P3, 3 * b + 1);
                float b3z = sc(P4, 3 * b + 2) - sc(P3, 3 * b + 2);
                float n1x = b1y * b2z - b1z * b2y;
                float n1y = b1z * b2x - b1x * b2z;
                float n1z = b1x * b2y - b1y * b2x;
                float n2x = b2y * b3z - b2z * b3y;
                float n2y = b2z * b3x - b2x * b3z;
                float n2z = b2x * b3y - b2y * b3x;
                float dot = n1x * n2x + n1y * n2y + n1z * n2z;
                float nn = (n1x * n1x + n1y * n1y + n1z * n1z) *
                           (n2x * n2x + n2y * n2y + n2z * n2z);
                float x = clamp1(dot * rsqrtf(fmaxf(nn, 1e-24f)));
                // cos(n*acos(x)) = T_n(x), n in [1,6]
                float Tp = 1.f, Tc = x, res = x;
#pragma unroll
                for (int kk = 2; kk <= 6; kk++) {
                    float Tn = 2.f * x * Tc - Tp;
                    Tp = Tc; Tc = Tn;
                    if (ord == kk) res = Tn;
                }
                acc[b] += 0.5f * V * (1.f - ctm * res);
            }
        }
    } else if (blk < s.e3) {
        // ---------------- inversion (Wilson) ----------------
        const int t = (blk - s.e2) * TPB + tid;
        if (t < s.NI) {
            const vi4 q = __builtin_nontemporal_load((const vi4*)iidx + t);  // i, central, k, l
            const float K = ntf(ik + t), c0 = ntf(ic0 + t), c1 = ntf(ic1 + t), c2 = ntf(ic2 + t);
            Slot CA = loadSlot<USE_WS>(cw, coords, N, q.y);
            Slot PI = loadSlot<USE_WS>(cw, coords, N, q.x);
            Slot PK = loadSlot<USE_WS>(cw, coords, N, q.z);
            Slot PL = loadSlot<USE_WS>(cw, coords, N, q.w);
#pragma unroll
            for (int b = 0; b < 8; b++) {
                float jix = sc(PI, 3 * b) - sc(CA, 3 * b);
                float jiy = sc(PI, 3 * b + 1) - sc(CA, 3 * b + 1);
                float jiz = sc(PI, 3 * b + 2) - sc(CA, 3 * b + 2);
                float jkx = sc(PK, 3 * b) - sc(CA, 3 * b);
                float jky = sc(PK, 3 * b + 1) - sc(CA, 3 * b + 1);
                float jkz = sc(PK, 3 * b + 2) - sc(CA, 3 * b + 2);
                float lx  = sc(PL, 3 * b) - sc(CA, 3 * b);
                float ly  = sc(PL, 3 * b + 1) - sc(CA, 3 * b + 1);
                float lz  = sc(PL, 3 * b + 2) - sc(CA, 3 * b + 2);
                float nx = jiy * jkz - jiz * jky;
                float ny = jiz * jkx - jix * jkz;
                float nz = jix * jky - jiy * jkx;
                float dot = nx * lx + ny * ly + nz * lz;
                float nn = (nx * nx + ny * ny + nz * nz) * (lx * lx + ly * ly + lz * lz);
                float cosY = clamp1(dot * rsqrtf(fmaxf(nn, 1e-24f)));
                float sinY = sqrtf(fmaxf(1.f - cosY * cosY, 0.f));
                acc[b] += K * (c0 + c1 * sinY + c2 * (2.f * sinY * sinY - 1.f));
            }
        }
    } else {
        // ---------------- vdW LJ: 2 pairs/thread, branchless, all loads up front ----
        const int t0 = (blk - s.e3) * (2 * TPB) + tid;
        const int t1 = t0 + TPB;
        const bool v0 = t0 < s.NC, v1 = t1 < s.NC;
        const int u0 = v0 ? t0 : 0;
        const int u1 = v1 ? t1 : 0;
        const vi2 ij0 = __builtin_nontemporal_load((const vi2*)nidx + u0);
        const vi2 ij1 = __builtin_nontemporal_load((const vi2*)nidx + u1);
        const float R0 = ntf(vmin + u0), D0 = ntf(vdep + u0), th0 = ntf(vthr + u0);
        const float R1 = ntf(vmin + u1), D1 = ntf(vdep + u1), th1 = ntf(vthr + u1);
        // Issue all 24 coord loads before any compute.
        Slot ci0 = loadSlot<USE_WS>(cw, coords, N, ij0.x);
        Slot cj0 = loadSlot<USE_WS>(cw, coords, N, ij0.y);
        Slot ci1 = loadSlot<USE_WS>(cw, coords, N, ij1.x);
        Slot cj1 = loadSlot<USE_WS>(cw, coords, N, ij1.y);
        const float R20 = R0 * R0, R21 = R1 * R1;
#pragma unroll
        for (int b = 0; b < 8; b++) {
            float dx = sc(ci0, 3 * b) - sc(cj0, 3 * b);
            float dy = sc(ci0, 3 * b + 1) - sc(cj0, 3 * b + 1);
            float dz = sc(ci0, 3 * b + 2) - sc(cj0, 3 * b + 2);
            float d2 = dx * dx + dy * dy + dz * dz;
            float x2 = R20 / fmaxf(d2, 1e-12f);
            float x6 = x2 * x2 * x2;
            float e = D0 * (x6 * x6 - 2.f * x6);
            if (v0 && d2 <= th0) acc[b] += e;

            float ex = sc(ci1, 3 * b) - sc(cj1, 3 * b);
            float ey = sc(ci1, 3 * b + 1) - sc(cj1, 3 * b + 1);
            float ez = sc(ci1, 3 * b + 2) - sc(cj1, 3 * b + 2);
            float f2 = ex * ex + ey * ey + ez * ez;
            float y2 = R21 / fmaxf(f2, 1e-12f);
            float y6 = y2 * y2 * y2;
            float g = D1 * (y6 * y6 - 2.f * y6);
            if (v1 && f2 <= th1) acc[b] += g;
        }
    }

    // ---------------- block reduction: 8 batch sums ----------------
    __shared__ float red[NWAVE][8];
    const int lane = tid & 63;
    const int wid = tid >> 6;
#pragma unroll
    for (int b = 0; b < 8; b++) {
        float v = acc[b];
#pragma unroll
        for (int off = 32; off > 0; off >>= 1) v += __shfl_down(v, off, 64);
        if (lane == 0) red[wid][b] = v;
    }
    __syncthreads();
    if (tid < 8) {
        float ssum = 0.f;
#pragma unroll
        for (int w = 0; w < NWAVE; w++) ssum += red[w][tid];
        atomicAdd(&out[tid], ssum);
    }
}

static inline int cdiv(int a, int b) { return (a + b - 1) / b; }

extern "C" void kernel_launch(void* const* d_in, const int* in_sizes, int n_in,
                              void* d_out, int out_size, void* d_ws, size_t ws_size,
                              hipStream_t stream) {
    const int B = out_size;  // expected 8 (kernel hard-codes 8 batch accumulators)
    const int NB = in_sizes[2], NA = in_sizes[5], NT = in_sizes[10],
              NI = in_sizes[14], NC = in_sizes[19];
    const int N = in_sizes[0] / (3 * B);

    const float* coords = (const float*)d_in[0];
    const int*   bidx = (const int*)d_in[1];
    const float* br0  = (const float*)d_in[2];
    const float* bk   = (const float*)d_in[3];
    const int*   aidx = (const int*)d_in[4];
    const float* ak   = (const float*)d_in[5];
    const float* ac0  = (const float*)d_in[6];
    const float* ac1  = (const float*)d_in[7];
    const float* ac2  = (const float*)d_in[8];
    const int*   tidx = (const int*)d_in[9];
    const float* tk   = (const float*)d_in[10];
    const int*   tord = (const int*)d_in[11];
    const float* tcos = (const float*)d_in[12];
    const int*   iidx = (const int*)d_in[13];
    const float* ik   = (const float*)d_in[14];
    const float* ic0  = (const float*)d_in[15];
    const float* ic1  = (const float*)d_in[16];
    const float* ic2  = (const float*)d_in[17];
    const int*   nidx = (const int*)d_in[18];
    const float* vmin = (const float*)d_in[19];
    const float* vdep = (const float*)d_in[20];
    const float* vthr = (const float*)d_in[21];

    const size_t ws_need = (size_t)N * 24 * sizeof(float);
    const bool use_ws = ws_size >= ws_need;
    float* cwp = (float*)d_ws;

    if (use_ws) {
        transpose_coords<<<cdiv(N, TPB), TPB, 0, stream>>>(coords, cwp, (float*)d_out, N);
    } else {
        hipMemsetAsync(d_out, 0, (size_t)out_size * sizeof(float), stream);
    }

    SegInfo s;
    s.NB = NB; s.NA = NA; s.NT = NT; s.NI = NI; s.NC = NC; s.N = N;
    s.e0 = cdiv(NB, TPB);
    s.e1 = s.e0 + cdiv(NA, TPB);
    s.e2 = s.e1 + cdiv(NT, TPB);
    s.e3 = s.e2 + cdiv(NI, TPB);
    s.e4 = s.e3 + cdiv(NC, 2 * TPB);

    if (use_ws) {
        uff_kernel<true><<<s.e4, TPB, 0, stream>>>(
            coords, cwp, bidx, br0, bk, aidx, ak, ac0, ac1, ac2,
            tidx, tk, tord, tcos, iidx, ik, ic0, ic1, ic2,
            nidx, vmin, vdep, vthr, (float*)d_out, s);
    } else {
        uff_kernel<false><<<s.e4, TPB, 0, stream>>>(
            coords, cwp, bidx, br0, bk, aidx, ak, ac0, ac1, ac2,
            tidx, tk, tord, tcos, iidx, ik, ic0, ic1, ic2,
            nidx, vmin, vdep, vthr, (float*)d_out, s);
    }
}

// Round 5
// 199.254 us; speedup vs baseline: 1.1770x; 1.1770x over previous
//
#include <hip/hip_runtime.h>

#define TPB 256
#define NWAVE (TPB / 64)
#define GRID_MAIN 2048

typedef int vi2 __attribute__((ext_vector_type(2)));
typedef int vi4 __attribute__((ext_vector_type(4)));

struct SegInfo {
    int e0, e1, e2, e3, e4;       // cumulative chunk-range ends: bond, angle, torsion, inversion, LJ
    int NB, NA, NT, NI, NC;
    int N;
};

__device__ __forceinline__ float clamp1(float x) {
    return fminf(fmaxf(x, -0.999999f), 0.999999f);
}

__device__ __forceinline__ float ntf(const float* p) { return __builtin_nontemporal_load(p); }
__device__ __forceinline__ int   nti(const int* p)   { return __builtin_nontemporal_load(p); }

// cw layout: float4[atom][8] — atom's 8 batch replicas contiguous, 128 B, 128B-aligned.
// 8 lanes of a term-group each load one aligned dwordx4 -> the group's gather
// coalesces to a single 128B region (2 line-requests) instead of 6 16B requests.
template <bool USE_WS>
__device__ __forceinline__ float4 loadC(const float4* __restrict__ cw,
                                        const float* __restrict__ coords,
                                        int N, int atom, int b) {
    if (USE_WS) {
        return cw[((size_t)atom << 3) + b];
    } else {
        const float* sp = coords + ((size_t)b * N + atom) * 3;
        return make_float4(sp[0], sp[1], sp[2], 0.f);
    }
}

// coords (B,N,3) -> cw float4[atom][8]; also zeroes d_out.
__global__ void __launch_bounds__(TPB) transpose_coords(const float* __restrict__ coords,
                                                        float4* __restrict__ cw,
                                                        float* __restrict__ out, int N) {
    const int a = blockIdx.x * TPB + threadIdx.x;
    if (blockIdx.x == 0 && threadIdx.x < 8) out[threadIdx.x] = 0.f;
    if (a >= N) return;
#pragma unroll
    for (int b = 0; b < 8; b++) {
        const float* sp = coords + ((size_t)b * N + a) * 3;
        cw[((size_t)a << 3) + b] = make_float4(ntf(sp), ntf(sp + 1), ntf(sp + 2), 0.f);
    }
}

template <bool USE_WS>
__global__ void __launch_bounds__(TPB) uff_kernel(
    const float* __restrict__ coords, const float4* __restrict__ cw,
    const int* __restrict__ bidx, const float* __restrict__ br0, const float* __restrict__ bk,
    const int* __restrict__ aidx, const float* __restrict__ ak,
    const float* __restrict__ ac0, const float* __restrict__ ac1, const float* __restrict__ ac2,
    const int* __restrict__ tidx, const float* __restrict__ tk,
    const int* __restrict__ tord, const float* __restrict__ tcos,
    const int* __restrict__ iidx, const float* __restrict__ ik,
    const float* __restrict__ ic0, const float* __restrict__ ic1, const float* __restrict__ ic2,
    const int* __restrict__ nidx, const float* __restrict__ vmin,
    const float* __restrict__ vdep, const float* __restrict__ vthr,
    float* __restrict__ out, SegInfo s)
{
    const int tid = threadIdx.x;
    const int N = s.N;
    const int b = tid & 7;        // this lane's batch
    const int gidx = tid >> 3;    // group (term slot) within block, 0..31
    float acc = 0.f;              // this lane's partial for batch b

    // Grid-stride over the chunk space (chunk = 32 terms handled by 256 threads).
    for (int c = blockIdx.x; c < s.e4; c += gridDim.x) {
        int kind, l;
        if (c < s.e0)      { kind = 0; l = c; }
        else if (c < s.e1) { kind = 1; l = c - s.e0; }
        else if (c < s.e2) { kind = 2; l = c - s.e1; }
        else if (c < s.e3) { kind = 3; l = c - s.e2; }
        else               { kind = 4; l = c - s.e3; }
        const int t = l * 32 + gidx;

        if (kind == 0) {
            // ---------------- bond stretch ----------------
            if (t < s.NB) {
                const vi2 ij = __builtin_nontemporal_load((const vi2*)bidx + t);
                const float r0 = ntf(br0 + t), k = ntf(bk + t);
                float4 ci = loadC<USE_WS>(cw, coords, N, ij.x, b);
                float4 cj = loadC<USE_WS>(cw, coords, N, ij.y, b);
                float dx = ci.x - cj.x, dy = ci.y - cj.y, dz = ci.z - cj.z;
                float dd = sqrtf(dx * dx + dy * dy + dz * dz) - r0;
                acc += 0.5f * k * dd * dd;
            }
        } else if (kind == 1) {
            // ---------------- angle bend ----------------
            if (t < s.NA) {
                const int i1 = nti(aidx + 3 * t), i2 = nti(aidx + 3 * t + 1), i3 = nti(aidx + 3 * t + 2);
                const float k = ntf(ak + t), c0 = ntf(ac0 + t), c1 = ntf(ac1 + t), c2 = ntf(ac2 + t);
                float4 P = loadC<USE_WS>(cw, coords, N, i1, b);
                float4 Q = loadC<USE_WS>(cw, coords, N, i2, b);
                float4 R = loadC<USE_WS>(cw, coords, N, i3, b);
                float ax = P.x - Q.x, ay = P.y - Q.y, az = P.z - Q.z;
                float bx = R.x - Q.x, by = R.y - Q.y, bz = R.z - Q.z;
                float dot = ax * bx + ay * by + az * bz;
                float nn = (ax * ax + ay * ay + az * az) * (bx * bx + by * by + bz * bz);
                float ct = clamp1(dot * rsqrtf(fmaxf(nn, 1e-24f)));
                float cs = ct * ct;
                float sb = fmaxf(1.f - cs, 1e-12f);
                acc += k * (c0 + c1 * ct + c2 * (cs - sb));
            }
        } else if (kind == 2) {
            // ---------------- torsion ----------------
            if (t < s.NT) {
                const vi4 q = __builtin_nontemporal_load((const vi4*)tidx + t);
                const float V = ntf(tk + t), ctm = ntf(tcos + t);
                const int ord = nti(tord + t);
                float4 P1 = loadC<USE_WS>(cw, coords, N, q.x, b);
                float4 P2 = loadC<USE_WS>(cw, coords, N, q.y, b);
                float4 P3 = loadC<USE_WS>(cw, coords, N, q.z, b);
                float4 P4 = loadC<USE_WS>(cw, coords, N, q.w, b);
                float b1x = P2.x - P1.x, b1y = P2.y - P1.y, b1z = P2.z - P1.z;
                float b2x = P3.x - P2.x, b2y = P3.y - P2.y, b2z = P3.z - P2.z;
                float b3x = P4.x - P3.x, b3y = P4.y - P3.y, b3z = P4.z - P3.z;
                float n1x = b1y * b2z - b1z * b2y;
                float n1y = b1z * b2x - b1x * b2z;
                float n1z = b1x * b2y - b1y * b2x;
                float n2x = b2y * b3z - b2z * b3y;
                float n2y = b2z * b3x - b2x * b3z;
                float n2z = b2x * b3y - b2y * b3x;
                float dot = n1x * n2x + n1y * n2y + n1z * n2z;
                float nn = (n1x * n1x + n1y * n1y + n1z * n1z) *
                           (n2x * n2x + n2y * n2y + n2z * n2z);
                float x = clamp1(dot * rsqrtf(fmaxf(nn, 1e-24f)));
                // cos(n*acos(x)) = T_n(x), n in [1,6]
                float Tp = 1.f, Tc = x, res = x;
#pragma unroll
                for (int kk = 2; kk <= 6; kk++) {
                    float Tn = 2.f * x * Tc - Tp;
                    Tp = Tc; Tc = Tn;
                    if (ord == kk) res = Tn;
                }
                acc += 0.5f * V * (1.f - ctm * res);
            }
        } else if (kind == 3) {
            // ---------------- inversion (Wilson) ----------------
            if (t < s.NI) {
                const vi4 q = __builtin_nontemporal_load((const vi4*)iidx + t);  // i, central, k, l
                const float K = ntf(ik + t), c0 = ntf(ic0 + t), c1 = ntf(ic1 + t), c2 = ntf(ic2 + t);
                float4 CA = loadC<USE_WS>(cw, coords, N, q.y, b);
                float4 PI = loadC<USE_WS>(cw, coords, N, q.x, b);
                float4 PK = loadC<USE_WS>(cw, coords, N, q.z, b);
                float4 PL = loadC<USE_WS>(cw, coords, N, q.w, b);
                float jix = PI.x - CA.x, jiy = PI.y - CA.y, jiz = PI.z - CA.z;
                float jkx = PK.x - CA.x, jky = PK.y - CA.y, jkz = PK.z - CA.z;
                float lx  = PL.x - CA.x, ly  = PL.y - CA.y, lz  = PL.z - CA.z;
                float nx = jiy * jkz - jiz * jky;
                float ny = jiz * jkx - jix * jkz;
                float nz = jix * jky - jiy * jkx;
                float dot = nx * lx + ny * ly + nz * lz;
                float nn = (nx * nx + ny * ny + nz * nz) * (lx * lx + ly * ly + lz * lz);
                float cosY = clamp1(dot * rsqrtf(fmaxf(nn, 1e-24f)));
                float sinY = sqrtf(fmaxf(1.f - cosY * cosY, 0.f));
                acc += K * (c0 + c1 * sinY + c2 * (2.f * sinY * sinY - 1.f));
            }
        } else {
            // ---------------- vdW LJ ----------------
            if (t < s.NC) {
                const vi2 ij = __builtin_nontemporal_load((const vi2*)nidx + t);
                const float R = ntf(vmin + t), D = ntf(vdep + t), thr = ntf(vthr + t);
                float4 ci = loadC<USE_WS>(cw, coords, N, ij.x, b);
                float4 cj = loadC<USE_WS>(cw, coords, N, ij.y, b);
                float dx = ci.x - cj.x, dy = ci.y - cj.y, dz = ci.z - cj.z;
                float d2 = dx * dx + dy * dy + dz * dz;
                float x2 = (R * R) / fmaxf(d2, 1e-12f);
                float x6 = x2 * x2 * x2;
                float e = D * (x6 * x6 - 2.f * x6);
                if (d2 <= thr) acc += e;
            }
        }
    }

    // ---------------- reduction: lanes with same (lane&7) hold same batch ----------------
    float v = acc;
    v += __shfl_down(v, 8, 64);
    v += __shfl_down(v, 16, 64);
    v += __shfl_down(v, 32, 64);
    // lanes 0..7 of each wave now hold batch 0..7 sums

    __shared__ float red[NWAVE][8];
    const int lane = tid & 63;
    const int wid = tid >> 6;
    if (lane < 8) red[wid][lane] = v;
    __syncthreads();
    if (tid < 8) {
        float ssum = 0.f;
#pragma unroll
        for (int w = 0; w < NWAVE; w++) ssum += red[w][tid];
        atomicAdd(&out[tid], ssum);
    }
}

static inline int cdiv(int a, int b) { return (a + b - 1) / b; }

extern "C" void kernel_launch(void* const* d_in, const int* in_sizes, int n_in,
                              void* d_out, int out_size, void* d_ws, size_t ws_size,
                              hipStream_t stream) {
    const int B = out_size;  // expected 8 (kernel hard-codes 8 batches)
    const int NB = in_sizes[2], NA = in_sizes[5], NT = in_sizes[10],
              NI = in_sizes[14], NC = in_sizes[19];
    const int N = in_sizes[0] / (3 * B);

    const float* coords = (const float*)d_in[0];
    const int*   bidx = (const int*)d_in[1];
    const float* br0  = (const float*)d_in[2];
    const float* bk   = (const float*)d_in[3];
    const int*   aidx = (const int*)d_in[4];
    const float* ak   = (const float*)d_in[5];
    const float* ac0  = (const float*)d_in[6];
    const float* ac1  = (const float*)d_in[7];
    const float* ac2  = (const float*)d_in[8];
    const int*   tidx = (const int*)d_in[9];
    const float* tk   = (const float*)d_in[10];
    const int*   tord = (const int*)d_in[11];
    const float* tcos = (const float*)d_in[12];
    const int*   iidx = (const int*)d_in[13];
    const float* ik   = (const float*)d_in[14];
    const float* ic0  = (const float*)d_in[15];
    const float* ic1  = (const float*)d_in[16];
    const float* ic2  = (const float*)d_in[17];
    const int*   nidx = (const int*)d_in[18];
    const float* vmin = (const float*)d_in[19];
    const float* vdep = (const float*)d_in[20];
    const float* vthr = (const float*)d_in[21];

    const size_t ws_need = (size_t)N * 8 * sizeof(float4);
    const bool use_ws = ws_size >= ws_need;
    float4* cw = (float4*)d_ws;

    if (use_ws) {
        transpose_coords<<<cdiv(N, TPB), TPB, 0, stream>>>(coords, cw, (float*)d_out, N);
    } else {
        hipMemsetAsync(d_out, 0, (size_t)out_size * sizeof(float), stream);
    }

    // chunk = 32 terms (256 threads, 8 lanes/term)
    SegInfo s;
    s.NB = NB; s.NA = NA; s.NT = NT; s.NI = NI; s.NC = NC; s.N = N;
    s.e0 = cdiv(NB, 32);
    s.e1 = s.e0 + cdiv(NA, 32);
    s.e2 = s.e1 + cdiv(NT, 32);
    s.e3 = s.e2 + cdiv(NI, 32);
    s.e4 = s.e3 + cdiv(NC, 32);

    const int grid = (s.e4 < GRID_MAIN) ? s.e4 : GRID_MAIN;

    if (use_ws) {
        uff_kernel<true><<<grid, TPB, 0, stream>>>(
            coords, cw, bidx, br0, bk, aidx, ak, ac0, ac1, ac2,
            tidx, tk, tord, tcos, iidx, ik, ic0, ic1, ic2,
            nidx, vmin, vdep, vthr, (float*)d_out, s);
    } else {
        uff_kernel<false><<<grid, TPB, 0, stream>>>(
            coords, cw, bidx, br0, bk, aidx, ak, ac0, ac1, ac2,
            tidx, tk, tord, tcos, iidx, ik, ic0, ic1, ic2,
            nidx, vmin, vdep, vthr, (float*)d_out, s);
    }
}

// Round 6
// 177.804 us; speedup vs baseline: 1.3190x; 1.1206x over previous
//
#include <hip/hip_runtime.h>

#define TPB 256
#define NWAVE (TPB / 64)
#define GRID_MAIN 2048

typedef int vi2 __attribute__((ext_vector_type(2)));
typedef int vi4 __attribute__((ext_vector_type(4)));

struct SegInfo {
    int cb, ca, ct, ci, cl;       // chunk counts: bond, angle, torsion, inversion, LJ(x2)
    int NB, NA, NT, NI, NC;
    int N;
};

__device__ __forceinline__ float clamp1(float x) {
    return fminf(fmaxf(x, -0.999999f), 0.999999f);
}

__device__ __forceinline__ float ntf(const float* p) { return __builtin_nontemporal_load(p); }

// group-of-8 broadcast: take lane (sl = lane & ~7)'s value
__device__ __forceinline__ float bcf(float v, int sl) { return __shfl(v, sl, 64); }
__device__ __forceinline__ int   bci(int v, int sl)   { return __shfl(v, sl, 64); }

// cw layout: float4[atom][8] — atom's 8 batch replicas contiguous (128 B aligned).
// 8 lanes of a term-group each load one dwordx4 -> one 128B region per gather.
template <bool USE_WS>
__device__ __forceinline__ float4 loadC(const float4* __restrict__ cw,
                                        const float* __restrict__ coords,
                                        int N, int atom, int b) {
    if (USE_WS) {
        return cw[((size_t)atom << 3) + b];
    } else {
        const float* sp = coords + ((size_t)b * N + atom) * 3;
        return make_float4(sp[0], sp[1], sp[2], 0.f);
    }
}

// coords (B,N,3) -> cw float4[atom][8]; also zeroes d_out.
__global__ void __launch_bounds__(TPB) transpose_coords(const float* __restrict__ coords,
                                                        float4* __restrict__ cw,
                                                        float* __restrict__ out, int N) {
    const int a = blockIdx.x * TPB + threadIdx.x;
    if (blockIdx.x == 0 && threadIdx.x < 8) out[threadIdx.x] = 0.f;
    if (a >= N) return;
#pragma unroll
    for (int b = 0; b < 8; b++) {
        const float* sp = coords + ((size_t)b * N + a) * 3;
        cw[((size_t)a << 3) + b] = make_float4(ntf(sp), ntf(sp + 1), ntf(sp + 2), 0.f);
    }
}

template <bool USE_WS>
__global__ void __launch_bounds__(TPB) uff_kernel(
    const float* __restrict__ coords, const float4* __restrict__ cw,
    const int* __restrict__ bidx, const float* __restrict__ br0, const float* __restrict__ bk,
    const int* __restrict__ aidx, const float* __restrict__ ak,
    const float* __restrict__ ac0, const float* __restrict__ ac1, const float* __restrict__ ac2,
    const int* __restrict__ tidx, const float* __restrict__ tk,
    const int* __restrict__ tord, const float* __restrict__ tcos,
    const int* __restrict__ iidx, const float* __restrict__ ik,
    const float* __restrict__ ic0, const float* __restrict__ ic1, const float* __restrict__ ic2,
    const int* __restrict__ nidx, const float* __restrict__ vmin,
    const float* __restrict__ vdep, const float* __restrict__ vthr,
    float* __restrict__ out, SegInfo s)
{
    const int tid = threadIdx.x;
    const int lane = tid & 63;
    const int b = tid & 7;        // this lane's batch
    const int g = tid >> 3;       // group (term slot) within block, 0..31
    const int sl = lane & ~7;     // group leader lane (within wave)
    const int N = s.N;
    float acc = 0.f;

    // ---------------- bond stretch ----------------
    for (int c = blockIdx.x; c < s.cb; c += gridDim.x) {
        const int t = c * 32 + g;
        const bool ok = t < s.NB;
        int ijx = 0, ijy = 0; float r0 = 0.f, k = 0.f;
        if (ok && b == 0) {
            const vi2 ij = __builtin_nontemporal_load((const vi2*)bidx + t);
            ijx = ij.x; ijy = ij.y; r0 = ntf(br0 + t); k = ntf(bk + t);
        }
        ijx = bci(ijx, sl); ijy = bci(ijy, sl); r0 = bcf(r0, sl); k = bcf(k, sl);
        float4 ci = loadC<USE_WS>(cw, coords, N, ijx, b);
        float4 cj = loadC<USE_WS>(cw, coords, N, ijy, b);
        float dx = ci.x - cj.x, dy = ci.y - cj.y, dz = ci.z - cj.z;
        float dd = sqrtf(dx * dx + dy * dy + dz * dz) - r0;
        if (ok) acc += 0.5f * k * dd * dd;
    }

    // ---------------- angle bend ----------------
    for (int c = blockIdx.x; c < s.ca; c += gridDim.x) {
        const int t = c * 32 + g;
        const bool ok = t < s.NA;
        int i1 = 0, i2 = 0, i3 = 0; float k = 0.f, c0 = 0.f, c1 = 0.f, c2 = 0.f;
        if (ok && b == 0) {
            i1 = aidx[3 * t]; i2 = aidx[3 * t + 1]; i3 = aidx[3 * t + 2];
            k = ntf(ak + t); c0 = ntf(ac0 + t); c1 = ntf(ac1 + t); c2 = ntf(ac2 + t);
        }
        i1 = bci(i1, sl); i2 = bci(i2, sl); i3 = bci(i3, sl);
        k = bcf(k, sl); c0 = bcf(c0, sl); c1 = bcf(c1, sl); c2 = bcf(c2, sl);
        float4 P = loadC<USE_WS>(cw, coords, N, i1, b);
        float4 Q = loadC<USE_WS>(cw, coords, N, i2, b);
        float4 R = loadC<USE_WS>(cw, coords, N, i3, b);
        float ax = P.x - Q.x, ay = P.y - Q.y, az = P.z - Q.z;
        float bx = R.x - Q.x, by = R.y - Q.y, bz = R.z - Q.z;
        float dot = ax * bx + ay * by + az * bz;
        float nn = (ax * ax + ay * ay + az * az) * (bx * bx + by * by + bz * bz);
        float ct = clamp1(dot * rsqrtf(fmaxf(nn, 1e-24f)));
        float cs = ct * ct;
        float sb = fmaxf(1.f - cs, 1e-12f);
        if (ok) acc += k * (c0 + c1 * ct + c2 * (cs - sb));
    }

    // ---------------- torsion ----------------
    for (int c = blockIdx.x; c < s.ct; c += gridDim.x) {
        const int t = c * 32 + g;
        const bool ok = t < s.NT;
        int q0 = 0, q1 = 0, q2 = 0, q3 = 0, ord = 1;
        float V = 0.f, ctm = 0.f;
        if (ok && b == 0) {
            const vi4 q = __builtin_nontemporal_load((const vi4*)tidx + t);
            q0 = q.x; q1 = q.y; q2 = q.z; q3 = q.w;
            V = ntf(tk + t); ctm = ntf(tcos + t);
            ord = __builtin_nontemporal_load(tord + t);
        }
        q0 = bci(q0, sl); q1 = bci(q1, sl); q2 = bci(q2, sl); q3 = bci(q3, sl);
        V = bcf(V, sl); ctm = bcf(ctm, sl); ord = bci(ord, sl);
        float4 P1 = loadC<USE_WS>(cw, coords, N, q0, b);
        float4 P2 = loadC<USE_WS>(cw, coords, N, q1, b);
        float4 P3 = loadC<USE_WS>(cw, coords, N, q2, b);
        float4 P4 = loadC<USE_WS>(cw, coords, N, q3, b);
        float b1x = P2.x - P1.x, b1y = P2.y - P1.y, b1z = P2.z - P1.z;
        float b2x = P3.x - P2.x, b2y = P3.y - P2.y, b2z = P3.z - P2.z;
        float b3x = P4.x - P3.x, b3y = P4.y - P3.y, b3z = P4.z - P3.z;
        float n1x = b1y * b2z - b1z * b2y;
        float n1y = b1z * b2x - b1x * b2z;
        float n1z = b1x * b2y - b1y * b2x;
        float n2x = b2y * b3z - b2z * b3y;
        float n2y = b2z * b3x - b2x * b3z;
        float n2z = b2x * b3y - b2y * b3x;
        float dot = n1x * n2x + n1y * n2y + n1z * n2z;
        float nn = (n1x * n1x + n1y * n1y + n1z * n1z) *
                   (n2x * n2x + n2y * n2y + n2z * n2z);
        float x = clamp1(dot * rsqrtf(fmaxf(nn, 1e-24f)));
        // cos(n*acos(x)) = T_n(x), n in [1,6]
        float Tp = 1.f, Tc = x, res = x;
#pragma unroll
        for (int kk = 2; kk <= 6; kk++) {
            float Tn = 2.f * x * Tc - Tp;
            Tp = Tc; Tc = Tn;
            if (ord == kk) res = Tn;
        }
        if (ok) acc += 0.5f * V * (1.f - ctm * res);
    }

    // ---------------- inversion (Wilson) ----------------
    for (int c = blockIdx.x; c < s.ci; c += gridDim.x) {
        const int t = c * 32 + g;
        const bool ok = t < s.NI;
        int q0 = 0, q1 = 0, q2 = 0, q3 = 0;
        float K = 0.f, c0 = 0.f, c1 = 0.f, c2 = 0.f;
        if (ok && b == 0) {
            const vi4 q = __builtin_nontemporal_load((const vi4*)iidx + t);  // i, central, k, l
            q0 = q.x; q1 = q.y; q2 = q.z; q3 = q.w;
            K = ntf(ik + t); c0 = ntf(ic0 + t); c1 = ntf(ic1 + t); c2 = ntf(ic2 + t);
        }
        q0 = bci(q0, sl); q1 = bci(q1, sl); q2 = bci(q2, sl); q3 = bci(q3, sl);
        K = bcf(K, sl); c0 = bcf(c0, sl); c1 = bcf(c1, sl); c2 = bcf(c2, sl);
        float4 CA = loadC<USE_WS>(cw, coords, N, q1, b);
        float4 PI = loadC<USE_WS>(cw, coords, N, q0, b);
        float4 PK = loadC<USE_WS>(cw, coords, N, q2, b);
        float4 PL = loadC<USE_WS>(cw, coords, N, q3, b);
        float jix = PI.x - CA.x, jiy = PI.y - CA.y, jiz = PI.z - CA.z;
        float jkx = PK.x - CA.x, jky = PK.y - CA.y, jkz = PK.z - CA.z;
        float lx  = PL.x - CA.x, ly  = PL.y - CA.y, lz  = PL.z - CA.z;
        float nx = jiy * jkz - jiz * jky;
        float ny = jiz * jkx - jix * jkz;
        float nz = jix * jky - jiy * jkx;
        float dot = nx * lx + ny * ly + nz * lz;
        float nn = (nx * nx + ny * ny + nz * nz) * (lx * lx + ly * ly + lz * lz);
        float cosY = clamp1(dot * rsqrtf(fmaxf(nn, 1e-24f)));
        float sinY = sqrtf(fmaxf(1.f - cosY * cosY, 0.f));
        if (ok) acc += K * (c0 + c1 * sinY + c2 * (2.f * sinY * sinY - 1.f));
    }

    // ---------------- vdW LJ: 2 terms per group per iteration ----------------
    for (int c = blockIdx.x; c < s.cl; c += gridDim.x) {
        const int t0 = c * 64 + g;
        const int t1 = t0 + 32;
        const bool ok0 = t0 < s.NC, ok1 = t1 < s.NC;
        int ax0 = 0, ay0 = 0, ax1 = 0, ay1 = 0;
        float R0 = 0.f, D0 = 0.f, th0 = 0.f, R1 = 0.f, D1 = 0.f, th1 = 0.f;
        if (ok0 && b == 0) {
            const vi2 ij = __builtin_nontemporal_load((const vi2*)nidx + t0);
            ax0 = ij.x; ay0 = ij.y;
            R0 = ntf(vmin + t0); D0 = ntf(vdep + t0); th0 = ntf(vthr + t0);
        }
        if (ok1 && b == 0) {
            const vi2 ij = __builtin_nontemporal_load((const vi2*)nidx + t1);
            ax1 = ij.x; ay1 = ij.y;
            R1 = ntf(vmin + t1); D1 = ntf(vdep + t1); th1 = ntf(vthr + t1);
        }
        ax0 = bci(ax0, sl); ay0 = bci(ay0, sl); ax1 = bci(ax1, sl); ay1 = bci(ay1, sl);
        R0 = bcf(R0, sl); D0 = bcf(D0, sl); th0 = bcf(th0, sl);
        R1 = bcf(R1, sl); D1 = bcf(D1, sl); th1 = bcf(th1, sl);
        float4 ci0 = loadC<USE_WS>(cw, coords, N, ax0, b);
        float4 cj0 = loadC<USE_WS>(cw, coords, N, ay0, b);
        float4 ci1 = loadC<USE_WS>(cw, coords, N, ax1, b);
        float4 cj1 = loadC<USE_WS>(cw, coords, N, ay1, b);
        {
            float dx = ci0.x - cj0.x, dy = ci0.y - cj0.y, dz = ci0.z - cj0.z;
            float d2 = dx * dx + dy * dy + dz * dz;
            float x2 = (R0 * R0) / fmaxf(d2, 1e-12f);
            float x6 = x2 * x2 * x2;
            float e = D0 * (x6 * x6 - 2.f * x6);
            if (ok0 && d2 <= th0) acc += e;
        }
        {
            float dx = ci1.x - cj1.x, dy = ci1.y - cj1.y, dz = ci1.z - cj1.z;
            float d2 = dx * dx + dy * dy + dz * dz;
            float x2 = (R1 * R1) / fmaxf(d2, 1e-12f);
            float x6 = x2 * x2 * x2;
            float e = D1 * (x6 * x6 - 2.f * x6);
            if (ok1 && d2 <= th1) acc += e;
        }
    }

    // ---------------- reduction: lanes with same (lane&7) hold same batch ----------------
    float v = acc;
    v += __shfl_down(v, 8, 64);
    v += __shfl_down(v, 16, 64);
    v += __shfl_down(v, 32, 64);
    // lanes 0..7 of each wave now hold batch 0..7 sums

    __shared__ float red[NWAVE][8];
    const int wid = tid >> 6;
    if (lane < 8) red[wid][lane] = v;
    __syncthreads();
    if (tid < 8) {
        float ssum = 0.f;
#pragma unroll
        for (int w = 0; w < NWAVE; w++) ssum += red[w][tid];
        atomicAdd(&out[tid], ssum);
    }
}

static inline int cdiv(int a, int b) { return (a + b - 1) / b; }

extern "C" void kernel_launch(void* const* d_in, const int* in_sizes, int n_in,
                              void* d_out, int out_size, void* d_ws, size_t ws_size,
                              hipStream_t stream) {
    const int B = out_size;  // expected 8 (kernel hard-codes 8 batches)
    const int NB = in_sizes[2], NA = in_sizes[5], NT = in_sizes[10],
              NI = in_sizes[14], NC = in_sizes[19];
    const int N = in_sizes[0] / (3 * B);

    const float* coords = (const float*)d_in[0];
    const int*   bidx = (const int*)d_in[1];
    const float* br0  = (const float*)d_in[2];
    const float* bk   = (const float*)d_in[3];
    const int*   aidx = (const int*)d_in[4];
    const float* ak   = (const float*)d_in[5];
    const float* ac0  = (const float*)d_in[6];
    const float* ac1  = (const float*)d_in[7];
    const float* ac2  = (const float*)d_in[8];
    const int*   tidx = (const int*)d_in[9];
    const float* tk   = (const float*)d_in[10];
    const int*   tord = (const int*)d_in[11];
    const float* tcos = (const float*)d_in[12];
    const int*   iidx = (const int*)d_in[13];
    const float* ik   = (const float*)d_in[14];
    const float* ic0  = (const float*)d_in[15];
    const float* ic1  = (const float*)d_in[16];
    const float* ic2  = (const float*)d_in[17];
    const int*   nidx = (const int*)d_in[18];
    const float* vmin = (const float*)d_in[19];
    const float* vdep = (const float*)d_in[20];
    const float* vthr = (const float*)d_in[21];

    const size_t ws_need = (size_t)N * 8 * sizeof(float4);
    const bool use_ws = ws_size >= ws_need;
    float4* cw = (float4*)d_ws;

    if (use_ws) {
        transpose_coords<<<cdiv(N, TPB), TPB, 0, stream>>>(coords, cw, (float*)d_out, N);
    } else {
        hipMemsetAsync(d_out, 0, (size_t)out_size * sizeof(float), stream);
    }

    SegInfo s;
    s.NB = NB; s.NA = NA; s.NT = NT; s.NI = NI; s.NC = NC; s.N = N;
    s.cb = cdiv(NB, 32);
    s.ca = cdiv(NA, 32);
    s.ct = cdiv(NT, 32);
    s.ci = cdiv(NI, 32);
    s.cl = cdiv(NC, 64);

    if (use_ws) {
        uff_kernel<true><<<GRID_MAIN, TPB, 0, stream>>>(
            coords, cw, bidx, br0, bk, aidx, ak, ac0, ac1, ac2,
            tidx, tk, tord, tcos, iidx, ik, ic0, ic1, ic2,
            nidx, vmin, vdep, vthr, (float*)d_out, s);
    } else {
        uff_kernel<false><<<GRID_MAIN, TPB, 0, stream>>>(
            coords, cw, bidx, br0, bk, aidx, ak, ac0, ac1, ac2,
            tidx, tk, tord, tcos, iidx, ik, ic0, ic1, ic2,
            nidx, vmin, vdep, vthr, (float*)d_out, s);
    }
}

// Round 7
// 168.768 us; speedup vs baseline: 1.3896x; 1.0535x over previous
//
#include <hip/hip_runtime.h>

#define TPB 256
#define NWAVE (TPB / 64)
#define CHUNK 256
#define GRID_MAIN 2048

typedef int vi2 __attribute__((ext_vector_type(2)));
typedef int vi4 __attribute__((ext_vector_type(4)));

struct SegInfo {
    int cb, ca, ct, ci, cl;       // chunk counts (CHUNK terms each) per kind
    int NB, NA, NT, NI, NC;
    int N;
};

__device__ __forceinline__ float clamp1(float x) {
    return fminf(fmaxf(x, -0.999999f), 0.999999f);
}

__device__ __forceinline__ float ntf(const float* p) { return __builtin_nontemporal_load(p); }

// cw layout: float4[atom][8] — atom's 8 batch replicas contiguous (128 B aligned).
// 8 lanes of a term-group each load one dwordx4 -> one 128B region per gather.
template <bool USE_WS>
__device__ __forceinline__ float4 loadC(const float4* __restrict__ cw,
                                        const float* __restrict__ coords,
                                        int N, int atom, int b) {
    if (USE_WS) {
        return cw[((size_t)atom << 3) + b];
    } else {
        const float* sp = coords + ((size_t)b * N + atom) * 3;
        return make_float4(sp[0], sp[1], sp[2], 0.f);
    }
}

// coords (B,N,3) -> cw float4[atom][8]; also zeroes d_out.
__global__ void __launch_bounds__(TPB) transpose_coords(const float* __restrict__ coords,
                                                        float4* __restrict__ cw,
                                                        float* __restrict__ out, int N) {
    const int a = blockIdx.x * TPB + threadIdx.x;
    if (blockIdx.x == 0 && threadIdx.x < 8) out[threadIdx.x] = 0.f;
    if (a >= N) return;
#pragma unroll
    for (int b = 0; b < 8; b++) {
        const float* sp = coords + ((size_t)b * N + a) * 3;
        cw[((size_t)a << 3) + b] = make_float4(ntf(sp), ntf(sp + 1), ntf(sp + 2), 0.f);
    }
}

template <bool USE_WS>
__global__ void __launch_bounds__(TPB) uff_kernel(
    const float* __restrict__ coords, const float4* __restrict__ cw,
    const int* __restrict__ bidx, const float* __restrict__ br0, const float* __restrict__ bk,
    const int* __restrict__ aidx, const float* __restrict__ ak,
    const float* __restrict__ ac0, const float* __restrict__ ac1, const float* __restrict__ ac2,
    const int* __restrict__ tidx, const float* __restrict__ tk,
    const int* __restrict__ tord, const float* __restrict__ tcos,
    const int* __restrict__ iidx, const float* __restrict__ ik,
    const float* __restrict__ ic0, const float* __restrict__ ic1, const float* __restrict__ ic2,
    const int* __restrict__ nidx, const float* __restrict__ vmin,
    const float* __restrict__ vdep, const float* __restrict__ vthr,
    float* __restrict__ out, SegInfo s)
{
    // Staged per-chunk term data: indices in sI, params in sP (8 KB total).
    __shared__ int4   sI[CHUNK];
    __shared__ float4 sP[CHUNK];

    const int tid = threadIdx.x;
    const int lane = tid & 63;
    const int b = tid & 7;        // this lane's batch
    const int g = tid >> 3;       // group (term slot) within block, 0..31
    const int N = s.N;
    float acc = 0.f;

    // ---------------- bond stretch ----------------
    for (int c = blockIdx.x; c < s.cb; c += gridDim.x) {
        const int base = c * CHUNK;
        {
            const int u = min(base + tid, s.NB - 1);
            const vi2 ij = __builtin_nontemporal_load((const vi2*)bidx + u);
            sI[tid] = make_int4(ij.x, ij.y, 0, 0);
            sP[tid] = make_float4(ntf(br0 + u), ntf(bk + u), 0.f, 0.f);
        }
        __syncthreads();
#pragma unroll 2
        for (int j = 0; j < 8; j++) {
            const int slot = g + 32 * j;
            const int4 q = sI[slot];
            const float4 p = sP[slot];
            float4 ci = loadC<USE_WS>(cw, coords, N, q.x, b);
            float4 cj = loadC<USE_WS>(cw, coords, N, q.y, b);
            float dx = ci.x - cj.x, dy = ci.y - cj.y, dz = ci.z - cj.z;
            float dd = sqrtf(dx * dx + dy * dy + dz * dz) - p.x;
            if (base + slot < s.NB) acc += 0.5f * p.y * dd * dd;
        }
        __syncthreads();
    }

    // ---------------- angle bend ----------------
    for (int c = blockIdx.x; c < s.ca; c += gridDim.x) {
        const int base = c * CHUNK;
        {
            const int u = min(base + tid, s.NA - 1);
            sI[tid] = make_int4(aidx[3 * u], aidx[3 * u + 1], aidx[3 * u + 2], 0);
            sP[tid] = make_float4(ntf(ak + u), ntf(ac0 + u), ntf(ac1 + u), ntf(ac2 + u));
        }
        __syncthreads();
#pragma unroll 2
        for (int j = 0; j < 8; j++) {
            const int slot = g + 32 * j;
            const int4 q = sI[slot];
            const float4 p = sP[slot];
            float4 P = loadC<USE_WS>(cw, coords, N, q.x, b);
            float4 Q = loadC<USE_WS>(cw, coords, N, q.y, b);
            float4 R = loadC<USE_WS>(cw, coords, N, q.z, b);
            float ax = P.x - Q.x, ay = P.y - Q.y, az = P.z - Q.z;
            float bx = R.x - Q.x, by = R.y - Q.y, bz = R.z - Q.z;
            float dot = ax * bx + ay * by + az * bz;
            float nn = (ax * ax + ay * ay + az * az) * (bx * bx + by * by + bz * bz);
            float ct = clamp1(dot * rsqrtf(fmaxf(nn, 1e-24f)));
            float cs = ct * ct;
            float sb = fmaxf(1.f - cs, 1e-12f);
            if (base + slot < s.NA) acc += p.x * (p.y + p.z * ct + p.w * (cs - sb));
        }
        __syncthreads();
    }

    // ---------------- torsion ----------------
    for (int c = blockIdx.x; c < s.ct; c += gridDim.x) {
        const int base = c * CHUNK;
        {
            const int u = min(base + tid, s.NT - 1);
            const vi4 q = __builtin_nontemporal_load((const vi4*)tidx + u);
            sI[tid] = make_int4(q.x, q.y, q.z, q.w);
            sP[tid] = make_float4(ntf(tk + u), ntf(tcos + u),
                                  __int_as_float(__builtin_nontemporal_load(tord + u)), 0.f);
        }
        __syncthreads();
#pragma unroll 2
        for (int j = 0; j < 8; j++) {
            const int slot = g + 32 * j;
            const int4 q = sI[slot];
            const float4 p = sP[slot];
            const int ord = __float_as_int(p.z);
            float4 P1 = loadC<USE_WS>(cw, coords, N, q.x, b);
            float4 P2 = loadC<USE_WS>(cw, coords, N, q.y, b);
            float4 P3 = loadC<USE_WS>(cw, coords, N, q.z, b);
            float4 P4 = loadC<USE_WS>(cw, coords, N, q.w, b);
            float b1x = P2.x - P1.x, b1y = P2.y - P1.y, b1z = P2.z - P1.z;
            float b2x = P3.x - P2.x, b2y = P3.y - P2.y, b2z = P3.z - P2.z;
            float b3x = P4.x - P3.x, b3y = P4.y - P3.y, b3z = P4.z - P3.z;
            float n1x = b1y * b2z - b1z * b2y;
            float n1y = b1z * b2x - b1x * b2z;
            float n1z = b1x * b2y - b1y * b2x;
            float n2x = b2y * b3z - b2z * b3y;
            float n2y = b2z * b3x - b2x * b3z;
            float n2z = b2x * b3y - b2y * b3x;
            float dot = n1x * n2x + n1y * n2y + n1z * n2z;
            float nn = (n1x * n1x + n1y * n1y + n1z * n1z) *
                       (n2x * n2x + n2y * n2y + n2z * n2z);
            float x = clamp1(dot * rsqrtf(fmaxf(nn, 1e-24f)));
            // cos(n*acos(x)) = T_n(x), n in [1,6]
            float Tp = 1.f, Tc = x, res = x;
#pragma unroll
            for (int kk = 2; kk <= 6; kk++) {
                float Tn = 2.f * x * Tc - Tp;
                Tp = Tc; Tc = Tn;
                if (ord == kk) res = Tn;
            }
            if (base + slot < s.NT) acc += 0.5f * p.x * (1.f - p.y * res);
        }
        __syncthreads();
    }

    // ---------------- inversion (Wilson) ----------------
    for (int c = blockIdx.x; c < s.ci; c += gridDim.x) {
        const int base = c * CHUNK;
        {
            const int u = min(base + tid, s.NI - 1);
            const vi4 q = __builtin_nontemporal_load((const vi4*)iidx + u);  // i, central, k, l
            sI[tid] = make_int4(q.x, q.y, q.z, q.w);
            sP[tid] = make_float4(ntf(ik + u), ntf(ic0 + u), ntf(ic1 + u), ntf(ic2 + u));
        }
        __syncthreads();
#pragma unroll 2
        for (int j = 0; j < 8; j++) {
            const int slot = g + 32 * j;
            const int4 q = sI[slot];
            const float4 p = sP[slot];
            float4 CA = loadC<USE_WS>(cw, coords, N, q.y, b);
            float4 PI = loadC<USE_WS>(cw, coords, N, q.x, b);
            float4 PK = loadC<USE_WS>(cw, coords, N, q.z, b);
            float4 PL = loadC<USE_WS>(cw, coords, N, q.w, b);
            float jix = PI.x - CA.x, jiy = PI.y - CA.y, jiz = PI.z - CA.z;
            float jkx = PK.x - CA.x, jky = PK.y - CA.y, jkz = PK.z - CA.z;
            float lx  = PL.x - CA.x, ly  = PL.y - CA.y, lz  = PL.z - CA.z;
            float nx = jiy * jkz - jiz * jky;
            float ny = jiz * jkx - jix * jkz;
            float nz = jix * jky - jiy * jkx;
            float dot = nx * lx + ny * ly + nz * lz;
            float nn = (nx * nx + ny * ny + nz * nz) * (lx * lx + ly * ly + lz * lz);
            float cosY = clamp1(dot * rsqrtf(fmaxf(nn, 1e-24f)));
            float sinY = sqrtf(fmaxf(1.f - cosY * cosY, 0.f));
            if (base + slot < s.NI) acc += p.x * (p.y + p.z * sinY + p.w * (2.f * sinY * sinY - 1.f));
        }
        __syncthreads();
    }

    // ---------------- vdW LJ: manual 2-way unroll for gather MLP ----------------
    for (int c = blockIdx.x; c < s.cl; c += gridDim.x) {
        const int base = c * CHUNK;
        {
            const int u = min(base + tid, s.NC - 1);
            const vi2 ij = __builtin_nontemporal_load((const vi2*)nidx + u);
            const float R = ntf(vmin + u);
            sI[tid] = make_int4(ij.x, ij.y, 0, 0);
            sP[tid] = make_float4(R * R, ntf(vdep + u), ntf(vthr + u), 0.f);
        }
        __syncthreads();
#pragma unroll
        for (int j = 0; j < 8; j += 2) {
            const int s0 = g + 32 * j, s1 = s0 + 32;
            const int4 q0 = sI[s0]; const float4 p0 = sP[s0];
            const int4 q1 = sI[s1]; const float4 p1 = sP[s1];
            float4 a0 = loadC<USE_WS>(cw, coords, N, q0.x, b);
            float4 b0 = loadC<USE_WS>(cw, coords, N, q0.y, b);
            float4 a1 = loadC<USE_WS>(cw, coords, N, q1.x, b);
            float4 b1 = loadC<USE_WS>(cw, coords, N, q1.y, b);
            {
                float dx = a0.x - b0.x, dy = a0.y - b0.y, dz = a0.z - b0.z;
                float d2 = dx * dx + dy * dy + dz * dz;
                float x2 = p0.x / fmaxf(d2, 1e-12f);
                float x6 = x2 * x2 * x2;
                float e = p0.y * (x6 * x6 - 2.f * x6);
                if (base + s0 < s.NC && d2 <= p0.z) acc += e;
            }
            {
                float dx = a1.x - b1.x, dy = a1.y - b1.y, dz = a1.z - b1.z;
                float d2 = dx * dx + dy * dy + dz * dz;
                float x2 = p1.x / fmaxf(d2, 1e-12f);
                float x6 = x2 * x2 * x2;
                float e = p1.y * (x6 * x6 - 2.f * x6);
                if (base + s1 < s.NC && d2 <= p1.z) acc += e;
            }
        }
        __syncthreads();
    }

    // ---------------- reduction: lanes with same (lane&7) hold same batch ----------------
    float v = acc;
    v += __shfl_down(v, 8, 64);
    v += __shfl_down(v, 16, 64);
    v += __shfl_down(v, 32, 64);
    // lanes 0..7 of each wave now hold batch 0..7 sums

    __shared__ float red[NWAVE][8];
    const int wid = tid >> 6;
    if (lane < 8) red[wid][lane] = v;
    __syncthreads();
    if (tid < 8) {
        float ssum = 0.f;
#pragma unroll
        for (int w = 0; w < NWAVE; w++) ssum += red[w][tid];
        atomicAdd(&out[tid], ssum);
    }
}

static inline int cdiv(int a, int b) { return (a + b - 1) / b; }

extern "C" void kernel_launch(void* const* d_in, const int* in_sizes, int n_in,
                              void* d_out, int out_size, void* d_ws, size_t ws_size,
                              hipStream_t stream) {
    const int B = out_size;  // expected 8 (kernel hard-codes 8 batches)
    const int NB = in_sizes[2], NA = in_sizes[5], NT = in_sizes[10],
              NI = in_sizes[14], NC = in_sizes[19];
    const int N = in_sizes[0] / (3 * B);

    const float* coords = (const float*)d_in[0];
    const int*   bidx = (const int*)d_in[1];
    const float* br0  = (const float*)d_in[2];
    const float* bk   = (const float*)d_in[3];
    const int*   aidx = (const int*)d_in[4];
    const float* ak   = (const float*)d_in[5];
    const float* ac0  = (const float*)d_in[6];
    const float* ac1  = (const float*)d_in[7];
    const float* ac2  = (const float*)d_in[8];
    const int*   tidx = (const int*)d_in[9];
    const float* tk   = (const float*)d_in[10];
    const int*   tord = (const int*)d_in[11];
    const float* tcos = (const float*)d_in[12];
    const int*   iidx = (const int*)d_in[13];
    const float* ik   = (const float*)d_in[14];
    const float* ic0  = (const float*)d_in[15];
    const float* ic1  = (const float*)d_in[16];
    const float* ic2  = (const float*)d_in[17];
    const int*   nidx = (const int*)d_in[18];
    const float* vmin = (const float*)d_in[19];
    const float* vdep = (const float*)d_in[20];
    const float* vthr = (const float*)d_in[21];

    const size_t ws_need = (size_t)N * 8 * sizeof(float4);
    const bool use_ws = ws_size >= ws_need;
    float4* cw = (float4*)d_ws;

    if (use_ws) {
        transpose_coords<<<cdiv(N, TPB), TPB, 0, stream>>>(coords, cw, (float*)d_out, N);
    } else {
        hipMemsetAsync(d_out, 0, (size_t)out_size * sizeof(float), stream);
    }

    SegInfo s;
    s.NB = NB; s.NA = NA; s.NT = NT; s.NI = NI; s.NC = NC; s.N = N;
    s.cb = cdiv(NB, CHUNK);
    s.ca = cdiv(NA, CHUNK);
    s.ct = cdiv(NT, CHUNK);
    s.ci = cdiv(NI, CHUNK);
    s.cl = cdiv(NC, CHUNK);

    if (use_ws) {
        uff_kernel<true><<<GRID_MAIN, TPB, 0, stream>>>(
            coords, cw, bidx, br0, bk, aidx, ak, ac0, ac1, ac2,
            tidx, tk, tord, tcos, iidx, ik, ic0, ic1, ic2,
            nidx, vmin, vdep, vthr, (float*)d_out, s);
    } else {
        uff_kernel<false><<<GRID_MAIN, TPB, 0, stream>>>(
            coords, cw, bidx, br0, bk, aidx, ak, ac0, ac1, ac2,
            tidx, tk, tord, tcos, iidx, ik, ic0, ic1, ic2,
            nidx, vmin, vdep, vthr, (float*)d_out, s);
    }
}